// Round 8
// baseline (192.627 us; speedup 1.0000x reference)
//
#include <hip/hip_runtime.h>
#include <hip/hip_bf16.h>
#include <math.h>

#define BB 4096
#define LL 50
#define NN 50
#define DD 128

typedef short bf16x8 __attribute__((ext_vector_type(8)));   // 8 bf16 = 4 VGPRs
typedef float f32x4  __attribute__((ext_vector_type(4)));

static __device__ inline unsigned short f32_to_bf16_rne(float f) {
    unsigned int u = __float_as_uint(f);
    u += 0x7FFFu + ((u >> 16) & 1u);   // round-nearest-even
    return (unsigned short)(u >> 16);
}
static __device__ inline unsigned int pack_bf16x2(float x, float y) {
    __hip_bfloat162 h = __float22bfloat162_rn(make_float2(x, y));  // v_cvt_pk_bf16_f32
    union { __hip_bfloat162 h2; unsigned int u; } c;
    c.h2 = h;
    return c.u;
}
// 8 consecutive fp32 in LDS -> bf16x8 fragment (low half of dword = even elem)
static __device__ inline bf16x8 frag_from_f32(const float* p) {
    float4 lo = *(const float4*)p;
    float4 hi = *(const float4*)(p + 4);
    union { unsigned int u[4]; bf16x8 v; } c;
    c.u[0] = pack_bf16x2(lo.x, lo.y);
    c.u[1] = pack_bf16x2(lo.z, lo.w);
    c.u[2] = pack_bf16x2(hi.x, hi.y);
    c.u[3] = pack_bf16x2(hi.z, hi.w);
    return c.v;
}
// Async global->LDS, 16B per lane. LDS dest = uniform base + lane*16.
static __device__ inline void async_copy16(const void* g, void* l) {
    __builtin_amdgcn_global_load_lds(
        (const __attribute__((address_space(1))) void*)g,
        (__attribute__((address_space(3))) void*)l, 16, 0, 0);
}

// Combined B fragments for mfma_f32_16x16x32_bf16 over extended K=256:
//   kk 0..3 -> W_seq rows, kk 4..7 -> W_last rows.
// ws[((kk*8+nt)*64+lane)*8+j] = W[(kk&3)*32+(lane>>4)*8+j][nt*16+(lane&15)]
__global__ void prep_w(const float* __restrict__ W_seq,
                       const float* __restrict__ W_last,
                       unsigned short* __restrict__ ws)
{
    int t = blockIdx.x * blockDim.x + threadIdx.x;   // 0..4095
    int lane = t & 63;
    int nt   = (t >> 6) & 7;
    int kk   = t >> 9;
    const float* W = (kk < 4) ? W_seq : W_last;
    int kb = (kk & 3) * 32 + (lane >> 4) * 8;
    int n  = nt * 16 + (lane & 15);
    unsigned short* dst = ws + (size_t)t * 8;
    #pragma unroll
    for (int j = 0; j < 8; ++j)
        dst[j] = f32_to_bf16_rne(W[(kb + j) * DD + n]);
}

// 4096 blocks x 1 batch, 4 waves. Wave w owns n-tiles {2w,2w+1}, all m-tiles.
// Node tile staged fp32 via async global_load_lds (no staging VGPRs, all 25
// chunks in flight at once). A-frags built from fp32 LDS with packed cvt.
__global__ __launch_bounds__(256, 4) void sess_attn(
    const int*   __restrict__ seq_idx,   // [B,L]
    const int*   __restrict__ mask,      // [B,L]
    const float* __restrict__ nodes,     // [B,N,D]
    const float* __restrict__ b_seq,     // [D]
    const float* __restrict__ W_alpha,   // [D]
    const unsigned short* __restrict__ wfrag,  // d_ws, combined B-frags
    float*       __restrict__ out)       // [B*D] v_n, then [B*D] session_graph
{
    const int b    = blockIdx.x;
    const int tid  = threadIdx.x;
    const int lane = tid & 63;
    const int wave = tid >> 6;
    const int col  = lane & 15;
    const int quad = lane >> 4;

    __shared__ __align__(16) float s_nf[NN * DD];   // 25600 B, flat fp32 tile
    __shared__ float s_alpha[64];
    __shared__ float s_cntf[64];
    __shared__ int   s_last;

    // ---- Async-stage the node tile: 25 x 1KB chunks, fire-and-forget. ----
    const char* gsrc = (const char*)(nodes + (size_t)b * (NN * DD));
    char* lbase = (char*)s_nf;
    for (int c = wave; c < 25; c += 4)
        async_copy16(gsrc + c * 1024 + lane * 16, lbase + c * 1024);

    // ---- All B fragments pre-barrier (no staging VGPRs to compete with). --
    const bf16x8* wsf = (const bf16x8*)wfrag;
    bf16x8 bfS[8], bfL[8];
    #pragma unroll
    for (int kk = 0; kk < 4; ++kk)
        #pragma unroll
        for (int j = 0; j < 2; ++j) {
            bfS[kk * 2 + j] = wsf[(size_t)(((kk    ) * 8 + wave * 2 + j) * 64 + lane)];
            bfL[kk * 2 + j] = wsf[(size_t)(((kk + 4) * 8 + wave * 2 + j) * 64 + lane)];
        }

    int pm = 0, pi = 0;
    if (tid < 64) {
        pm = (tid < LL) ? mask[b * LL + tid]    : 0;
        pi = (tid < LL) ? seq_idx[b * LL + tid] : 0;
    }

    float bb_r[2], wa_r[2];
    #pragma unroll
    for (int j = 0; j < 2; ++j) {
        int n = (wave * 2 + j) * 16 + col;
        bb_r[j] = b_seq[n];
        wa_r[j] = W_alpha[n];
    }

    if (tid < 64) { s_alpha[tid] = 0.f; s_cntf[tid] = 0.f; }

    // ---- Wave 0: seq_len, last index, histogram (register-only + LDS). ----
    if (tid < 64) {
        int mm = pm;
        mm += __shfl_xor(mm, 1);  mm += __shfl_xor(mm, 2);
        mm += __shfl_xor(mm, 4);  mm += __shfl_xor(mm, 8);
        mm += __shfl_xor(mm, 16); mm += __shfl_xor(mm, 32);
        int j = mm - 1;
        if (j < 0) j += LL;                 // JAX negative-index wrap
        int li = __shfl(pi, j);
        if (tid == 0) s_last = li;
        if (tid < LL && pm) atomicAdd(&s_cntf[pi], (float)pm);
    }
    __syncthreads();   // DMA tile drained, s_last/s_cntf/s_alpha visible

    const int last = s_last;

    // ---- v_n part first (bfL dies early, keeps peak VGPR in budget). ----
    // One A-tile serves every m (all rows = v_n); bias folded into init.
    f32x4 accV[2];
    #pragma unroll
    for (int j = 0; j < 2; ++j)
        accV[j] = (f32x4){bb_r[j], bb_r[j], bb_r[j], bb_r[j]};
    #pragma unroll
    for (int kk = 0; kk < 4; ++kk) {
        bf16x8 av = frag_from_f32(&s_nf[last * DD + kk * 32 + quad * 8]);
        #pragma unroll
        for (int j = 0; j < 2; ++j)
            accV[j] = __builtin_amdgcn_mfma_f32_16x16x32_bf16(
                av, bfL[kk * 2 + j], accV[j], 0, 0, 0);
    }

    // ---- W_seq MFMA loop (32 MFMAs/wave). A rows 50..63 are stale LDS;
    // their alpha rows are discarded below (row<NN), rows are independent.
    f32x4 acc[4][2];
    #pragma unroll
    for (int m = 0; m < 4; ++m)
        #pragma unroll
        for (int j = 0; j < 2; ++j)
            acc[m][j] = (f32x4){0.f, 0.f, 0.f, 0.f};

    #pragma unroll
    for (int kk = 0; kk < 4; ++kk) {
        bf16x8 a[4];
        #pragma unroll
        for (int m = 0; m < 4; ++m) {
            int row = m * 16 + col;
            a[m] = frag_from_f32(&s_nf[row * DD + kk * 32 + quad * 8]);
        }
        #pragma unroll
        for (int j = 0; j < 2; ++j)
            #pragma unroll
            for (int m = 0; m < 4; ++m)
                acc[m][j] = __builtin_amdgcn_mfma_f32_16x16x32_bf16(
                    a[m], bfS[kk * 2 + j], acc[m][j], 0, 0, 0);
    }

    // ---- Epilogue: alpha[row] += sum_cols sigmoid(acc+accV)*W_alpha. ----
    // C layout: col = lane&15, row = m*16 + quad*4 + r.
    #pragma unroll
    for (int m = 0; m < 4; ++m) {
        float pr[4] = {0.f, 0.f, 0.f, 0.f};
        #pragma unroll
        for (int j = 0; j < 2; ++j) {
            float wa = wa_r[j];
            #pragma unroll
            for (int r = 0; r < 4; ++r) {
                float x = acc[m][j][r] + accV[j][r];
                float sig = __builtin_amdgcn_rcpf(1.f + __expf(-x));
                pr[r] = fmaf(sig, wa, pr[r]);
            }
        }
        #pragma unroll
        for (int r = 0; r < 4; ++r) {
            float vv = pr[r];
            vv += __shfl_xor(vv, 1);
            vv += __shfl_xor(vv, 2);
            vv += __shfl_xor(vv, 4);
            vv += __shfl_xor(vv, 8);
            int row = m * 16 + quad * 4 + r;
            if (col == 0 && row < NN) atomicAdd(&s_alpha[row], vv);
        }
    }
    __syncthreads();   // s_alpha complete

    // ---- Outputs: exact fp32 from the LDS tile. ----
    if (tid < DD) {
        float acc2 = 0.f;
        #pragma unroll 10
        for (int n = 0; n < NN; ++n)
            acc2 = fmaf(s_cntf[n] * s_alpha[n], s_nf[n * DD + tid], acc2);
        out[(size_t)BB * DD + (size_t)b * DD + tid] = acc2;
        out[(size_t)b * DD + tid] = s_nf[last * DD + tid];   // v_n exact
    }
}

extern "C" void kernel_launch(void* const* d_in, const int* in_sizes, int n_in,
                              void* d_out, int out_size, void* d_ws, size_t ws_size,
                              hipStream_t stream) {
    const int*   seq     = (const int*)  d_in[0];
    const int*   mask    = (const int*)  d_in[1];
    const float* nodes   = (const float*)d_in[2];
    // d_in[3] = batch_size scalar (shapes compile-time fixed)
    const float* W_last  = (const float*)d_in[4];
    const float* W_seq   = (const float*)d_in[5];
    const float* b_seq   = (const float*)d_in[6];
    const float* W_alpha = (const float*)d_in[7];
    float*       out     = (float*)      d_out;

    unsigned short* wsf = (unsigned short*)d_ws;   // 64 KB combined B-fragments

    prep_w<<<16, 256, 0, stream>>>(W_seq, W_last, wsf);
    sess_attn<<<BB, 256, 0, stream>>>(seq, mask, nodes, b_seq, W_alpha, wsf, out);
}